// Round 9
// baseline (2500.013 us; speedup 1.0000x reference)
//
#include <hip/hip_runtime.h>

#define CUBE 32

typedef _Float16 half2_t __attribute__((ext_vector_type(2)));

__device__ __forceinline__ float sgpr_f(float v) {
    int i = __builtin_amdgcn_readfirstlane(__float_as_int(v));
    return __int_as_float(i);
}
// pack two f32 -> half2 held uniformly (SGPR via readfirstlane)
__device__ __forceinline__ half2_t sgpr_h2(float a, float b) {
    union { half2_t h; int i; } u;
    u.h = half2_t{(_Float16)a, (_Float16)b};
    u.i = __builtin_amdgcn_readfirstlane(u.i);
    return u.h;
}

// ---------------- Kernel A: surface = x @ W_in^T + b_in ----------------
__global__ __launch_bounds__(256) void in_gemm(
    const float* __restrict__ x,
    const float* __restrict__ W_in,
    const float* __restrict__ b_in,
    float* __restrict__ surface)
{
    __shared__ __align__(16) float As[16][68];
    __shared__ __align__(16) float Bs[16][68];
    const int t  = threadIdx.x;
    const int tx = t & 15, ty = t >> 4;
    const int bn = blockIdx.x * 64;
    const int bb = blockIdx.y * 64;

    float acc[4][4];
#pragma unroll
    for (int i = 0; i < 4; ++i)
#pragma unroll
        for (int j = 0; j < 4; ++j) acc[i][j] = 0.0f;

    for (int k0 = 0; k0 < 784; k0 += 16) {
        const int e  = t * 4;
        const int r  = e >> 4;
        const int kk = e & 15;
        float4 av = *(const float4*)&x[(size_t)(bb + r) * 784 + k0 + kk];
        float4 bv = *(const float4*)&W_in[(size_t)(bn + r) * 784 + k0 + kk];
        As[kk + 0][r] = av.x; As[kk + 1][r] = av.y; As[kk + 2][r] = av.z; As[kk + 3][r] = av.w;
        Bs[kk + 0][r] = bv.x; Bs[kk + 1][r] = bv.y; Bs[kk + 2][r] = bv.z; Bs[kk + 3][r] = bv.w;
        __syncthreads();
#pragma unroll
        for (int kki = 0; kki < 16; ++kki) {
            float4 a = *(const float4*)&As[kki][ty * 4];
            float4 b = *(const float4*)&Bs[kki][tx * 4];
            float aa[4] = {a.x, a.y, a.z, a.w};
            float bbv[4] = {b.x, b.y, b.z, b.w};
#pragma unroll
            for (int i = 0; i < 4; ++i)
#pragma unroll
                for (int j = 0; j < 4; ++j)
                    acc[i][j] = fmaf(aa[i], bbv[j], acc[i][j]);
        }
        __syncthreads();
    }
#pragma unroll
    for (int i = 0; i < 4; ++i) {
        const int row = bb + ty * 4 + i;
#pragma unroll
        for (int j = 0; j < 4; ++j) {
            const int col = bn + tx * 4 + j;
            surface[(size_t)row * 1024 + col] = acc[i][j] + b_in[col];
        }
    }
}

// ---------------- Kernel B: fp16-state cube evolution + output GEMM ----------
// Structure from r7 (state-in-LDS, in-place per-plane update, 512 thr × 2
// voxels), state stored _Float16 (74 KB -> 2 blocks/CU), conv via
// v_dot2_f32_f16 (f16 products, f32 accumulate).
// r8 bug (absmax 0.26): the in-place blend used A1.y/B1.x — plane p's center —
// instead of the CARRIED center of plane q=p-1 (cc0/cc1, set at end of
// PLANE(q)). Fixed: blend uses cc0/cc1, exactly like r7's passing f32 version.

#define REP32(M) M(0)M(1)M(2)M(3)M(4)M(5)M(6)M(7)M(8)M(9)M(10)M(11)M(12)M(13)M(14)M(15)M(16)M(17)M(18)M(19)M(20)M(21)M(22)M(23)M(24)M(25)M(26)M(27)M(28)M(29)M(30)M(31)

// Window for the thread's voxel pair (x = 2tx, 2tx+1; halo coords x' = x+1):
// cols 2tx..2tx+3 per row as two half2: A=(x-1,x0), B=(x1,x2).
// v0 = w0*A.lo + w1*A.hi + w2*B.lo = dot2((w0,w1),A) + dot2((w2,0),B)
// v1 = w0*A.hi + w1*B.lo + w2*B.hi = dot2((0,w0),A) + dot2((w1,w2),B)
// Slot n: 0 -> output p+1 (cw0-8), 1 -> output p (cw9-17), 2 -> output p-1.
#define ROWACC(n, r, A, B, a0, a1)                                             \
    a0 = __builtin_amdgcn_fdot2(wA_##n##_##r, A, a0, false);                   \
    a0 = __builtin_amdgcn_fdot2(wB_##n##_##r, B, a0, false);                   \
    a1 = __builtin_amdgcn_fdot2(wC_##n##_##r, A, a1, false);                   \
    a1 = __builtin_amdgcn_fdot2(wD_##n##_##r, B, a1, false);

#define PLANE(p, q, aN0, aN1, aC0, aC1, aP0, aP1) {                            \
    __syncthreads();                                                           \
    nb_##p = *(const float2*)&nbias[(p) * 1024 + nboff];                       \
    const half2_t A0 = *(const half2_t*)&S[p][ty + 0][tx2];                    \
    const half2_t B0 = *(const half2_t*)&S[p][ty + 0][tx2 + 2];                \
    const half2_t A1 = *(const half2_t*)&S[p][ty + 1][tx2];                    \
    const half2_t B1 = *(const half2_t*)&S[p][ty + 1][tx2 + 2];                \
    const half2_t A2 = *(const half2_t*)&S[p][ty + 2][tx2];                    \
    const half2_t B2 = *(const half2_t*)&S[p][ty + 2][tx2 + 2];                \
    if ((p) < 31) {                                                            \
        ROWACC(0, 0, A0, B0, aN0, aN1)                                         \
        ROWACC(0, 1, A1, B1, aN0, aN1)                                         \
        ROWACC(0, 2, A2, B2, aN0, aN1)                                         \
    }                                                                          \
    ROWACC(1, 0, A0, B0, aC0, aC1)                                             \
    ROWACC(1, 1, A1, B1, aC0, aC1)                                             \
    ROWACC(1, 2, A2, B2, aC0, aC1)                                             \
    if ((p) >= 1) {                                                            \
        ROWACC(2, 0, A0, B0, aP0, aP1)                                         \
        ROWACC(2, 1, A1, B1, aP0, aP1)                                         \
        ROWACC(2, 2, A2, B2, aP0, aP1)                                         \
        const float pre0 = aP0 + nb_##q.x + (((q) == 0) ? sf0 : 0.0f);         \
        const float pre1 = aP1 + nb_##q.y + (((q) == 0) ? sf1 : 0.0f);         \
        const float h0 = 1.0f - 2.0f * __builtin_amdgcn_rcpf(                  \
            __builtin_amdgcn_exp2f(pre0 * 2.8853900817779268f) + 1.0f);        \
        const float h1 = 1.0f - 2.0f * __builtin_amdgcn_rcpf(                  \
            __builtin_amdgcn_exp2f(pre1 * 2.8853900817779268f) + 1.0f);        \
        S[q][ty + 1][tx2 + 1] = (_Float16)(0.5f * (cc0 + h0));                 \
        S[q][ty + 1][tx2 + 2] = (_Float16)(0.5f * (cc1 + h1));                 \
        aP0 = 0.0f; aP1 = 0.0f;                                                \
    }                                                                          \
    cc0 = (float)A1.y; cc1 = (float)B1.x;                                      \
}

__global__ __launch_bounds__(512) void cube_evolve(
    const float* __restrict__ surface,   // [1024][1024]
    const float* __restrict__ conv_w,    // [27]  (kd,ky,kx)
    const float* __restrict__ nbias,     // [32768] (d,y,x)
    const float* __restrict__ W_out,     // [10][32768]
    const float* __restrict__ b_out,     // [10]
    const int*   __restrict__ steps_p,   // [1]
    float* __restrict__ out)             // [1024][10]
{
    __shared__ __align__(16) _Float16 S[32][34][34];   // 73,984 B -> 2 blocks/CU
    __shared__ float red[10][8];

    const int b   = blockIdx.x;
    const int tx  = threadIdx.x;         // 0..15, owns x = 2tx, 2tx+1
    const int ty  = threadIdx.y;         // 0..31
    const int tid = ty * 16 + tx;
    const int tx2 = tx * 2;              // halo-coord base of the 4-wide window
    const int nboff = ty * 32 + tx2;
    const int steps = steps_p[0];

    // zero state + halos (halo row 0/33, col 0/33 stay zero forever)
    for (int i = tid; i < 32 * 34 * 34 / 2; i += 512) ((int*)S)[i] = 0;

    // conv weights -> f32 uniforms, then packed f16-pair uniforms (SGPRs)
    const float cw0  = sgpr_f(conv_w[0]),  cw1  = sgpr_f(conv_w[1]),  cw2  = sgpr_f(conv_w[2]);
    const float cw3  = sgpr_f(conv_w[3]),  cw4  = sgpr_f(conv_w[4]),  cw5  = sgpr_f(conv_w[5]);
    const float cw6  = sgpr_f(conv_w[6]),  cw7  = sgpr_f(conv_w[7]),  cw8  = sgpr_f(conv_w[8]);
    const float cw9  = sgpr_f(conv_w[9]),  cw10 = sgpr_f(conv_w[10]), cw11 = sgpr_f(conv_w[11]);
    const float cw12 = sgpr_f(conv_w[12]), cw13 = sgpr_f(conv_w[13]), cw14 = sgpr_f(conv_w[14]);
    const float cw15 = sgpr_f(conv_w[15]), cw16 = sgpr_f(conv_w[16]), cw17 = sgpr_f(conv_w[17]);
    const float cw18 = sgpr_f(conv_w[18]), cw19 = sgpr_f(conv_w[19]), cw20 = sgpr_f(conv_w[20]);
    const float cw21 = sgpr_f(conv_w[21]), cw22 = sgpr_f(conv_w[22]), cw23 = sgpr_f(conv_w[23]);
    const float cw24 = sgpr_f(conv_w[24]), cw25 = sgpr_f(conv_w[25]), cw26 = sgpr_f(conv_w[26]);

#define MKW(n, r, wa, wb, wc)                                                  \
    const half2_t wA_##n##_##r = sgpr_h2(wa, wb);                              \
    const half2_t wB_##n##_##r = sgpr_h2(wc, 0.0f);                            \
    const half2_t wC_##n##_##r = sgpr_h2(0.0f, wa);                            \
    const half2_t wD_##n##_##r = sgpr_h2(wb, wc);
    MKW(0, 0, cw0,  cw1,  cw2 )  MKW(0, 1, cw3,  cw4,  cw5 )  MKW(0, 2, cw6,  cw7,  cw8 )
    MKW(1, 0, cw9,  cw10, cw11)  MKW(1, 1, cw12, cw13, cw14)  MKW(1, 2, cw15, cw16, cw17)
    MKW(2, 0, cw18, cw19, cw20)  MKW(2, 1, cw21, cw22, cw23)  MKW(2, 2, cw24, cw25, cw26)
#undef MKW

    const float2 sfv = *(const float2*)&surface[(size_t)b * 1024 + nboff];
    const float sf0 = sfv.x, sf1 = sfv.y;

    for (int st = 0; st < steps; ++st) {
#define DECL_NB(d) float2 nb_##d;
        REP32(DECL_NB)
#undef DECL_NB
        float aX0 = 0.f, aX1 = 0.f, aY0 = 0.f, aY1 = 0.f, aZ0 = 0.f, aZ1 = 0.f;
        float cc0 = 0.f, cc1 = 0.f;
        // slot rotation (period 3): p%3==0 -> (Y,X,Z); 1 -> (Z,Y,X); 2 -> (X,Z,Y)
        PLANE( 0,  0, aY0, aY1, aX0, aX1, aZ0, aZ1)
        PLANE( 1,  0, aZ0, aZ1, aY0, aY1, aX0, aX1)
        PLANE( 2,  1, aX0, aX1, aZ0, aZ1, aY0, aY1)
        PLANE( 3,  2, aY0, aY1, aX0, aX1, aZ0, aZ1)
        PLANE( 4,  3, aZ0, aZ1, aY0, aY1, aX0, aX1)
        PLANE( 5,  4, aX0, aX1, aZ0, aZ1, aY0, aY1)
        PLANE( 6,  5, aY0, aY1, aX0, aX1, aZ0, aZ1)
        PLANE( 7,  6, aZ0, aZ1, aY0, aY1, aX0, aX1)
        PLANE( 8,  7, aX0, aX1, aZ0, aZ1, aY0, aY1)
        PLANE( 9,  8, aY0, aY1, aX0, aX1, aZ0, aZ1)
        PLANE(10,  9, aZ0, aZ1, aY0, aY1, aX0, aX1)
        PLANE(11, 10, aX0, aX1, aZ0, aZ1, aY0, aY1)
        PLANE(12, 11, aY0, aY1, aX0, aX1, aZ0, aZ1)
        PLANE(13, 12, aZ0, aZ1, aY0, aY1, aX0, aX1)
        PLANE(14, 13, aX0, aX1, aZ0, aZ1, aY0, aY1)
        PLANE(15, 14, aY0, aY1, aX0, aX1, aZ0, aZ1)
        PLANE(16, 15, aZ0, aZ1, aY0, aY1, aX0, aX1)
        PLANE(17, 16, aX0, aX1, aZ0, aZ1, aY0, aY1)
        PLANE(18, 17, aY0, aY1, aX0, aX1, aZ0, aZ1)
        PLANE(19, 18, aZ0, aZ1, aY0, aY1, aX0, aX1)
        PLANE(20, 19, aX0, aX1, aZ0, aZ1, aY0, aY1)
        PLANE(21, 20, aY0, aY1, aX0, aX1, aZ0, aZ1)
        PLANE(22, 21, aZ0, aZ1, aY0, aY1, aX0, aX1)
        PLANE(23, 22, aX0, aX1, aZ0, aZ1, aY0, aY1)
        PLANE(24, 23, aY0, aY1, aX0, aX1, aZ0, aZ1)
        PLANE(25, 24, aZ0, aZ1, aY0, aY1, aX0, aX1)
        PLANE(26, 25, aX0, aX1, aZ0, aZ1, aY0, aY1)
        PLANE(27, 26, aY0, aY1, aX0, aX1, aZ0, aZ1)
        PLANE(28, 27, aZ0, aZ1, aY0, aY1, aX0, aX1)
        PLANE(29, 28, aX0, aX1, aZ0, aZ1, aY0, aY1)
        PLANE(30, 29, aY0, aY1, aX0, aX1, aZ0, aZ1)
        PLANE(31, 30, aZ0, aZ1, aY0, aY1, aX0, aX1)
        { // finalize output plane 31 (slot Y: plane30 kd=0 + plane31 kd=1)
            const float pre0 = aY0 + nb_31.x;
            const float pre1 = aY1 + nb_31.y;
            const float h0 = 1.0f - 2.0f * __builtin_amdgcn_rcpf(
                __builtin_amdgcn_exp2f(pre0 * 2.8853900817779268f) + 1.0f);
            const float h1 = 1.0f - 2.0f * __builtin_amdgcn_rcpf(
                __builtin_amdgcn_exp2f(pre1 * 2.8853900817779268f) + 1.0f);
            __syncthreads();   // all reads of S[31] (PLANE 31) done before overwrite
            S[31][ty + 1][tx2 + 1] = (_Float16)(0.5f * (cc0 + h0));
            S[31][ty + 1][tx2 + 2] = (_Float16)(0.5f * (cc1 + h1));
        }
    }
    __syncthreads();   // state complete & visible

    // ---- fused output GEMM: out[b][o] = sum_flat s * W_out[o][flat] + b_out[o]
    float p0 = 0.f, p1 = 0.f, p2 = 0.f, p3 = 0.f, p4 = 0.f;
    float p5 = 0.f, p6 = 0.f, p7 = 0.f, p8 = 0.f, p9 = 0.f;
    const int base = tid * 4;
#pragma unroll 4
    for (int j = 0; j < 16; ++j) {
        const int idx = base + j * 2048;
        const int d   = idx >> 10;
        const int rem = idx & 1023;
        const int yy  = rem >> 5;
        const int xx  = rem & 31;
        const float s0v = (float)S[d][yy + 1][xx + 1];
        const float s1v = (float)S[d][yy + 1][xx + 2];
        const float s2v = (float)S[d][yy + 1][xx + 3];
        const float s3v = (float)S[d][yy + 1][xx + 4];
#define OACC(o) { const float4 wv = *(const float4*)&W_out[(size_t)(o) * 32768 + idx]; \
        p##o = fmaf(s0v, wv.x, p##o); p##o = fmaf(s1v, wv.y, p##o);            \
        p##o = fmaf(s2v, wv.z, p##o); p##o = fmaf(s3v, wv.w, p##o); }
        OACC(0) OACC(1) OACC(2) OACC(3) OACC(4)
        OACC(5) OACC(6) OACC(7) OACC(8) OACC(9)
#undef OACC
    }

    const int lane = tid & 63, wvi = tid >> 6;
#define RED(o) { float t = p##o;                                               \
    t += __shfl_down(t, 32, 64); t += __shfl_down(t, 16, 64);                  \
    t += __shfl_down(t, 8, 64);  t += __shfl_down(t, 4, 64);                   \
    t += __shfl_down(t, 2, 64);  t += __shfl_down(t, 1, 64);                   \
    if (lane == 0) red[o][wvi] = t; }
    RED(0) RED(1) RED(2) RED(3) RED(4) RED(5) RED(6) RED(7) RED(8) RED(9)
#undef RED
    __syncthreads();
    if (tid < 10) {
        float sum = b_out[tid];
#pragma unroll
        for (int w8 = 0; w8 < 8; ++w8) sum += red[tid][w8];
        out[(size_t)b * 10 + tid] = sum;
    }
}

// ---------------- launcher ----------------
extern "C" void kernel_launch(void* const* d_in, const int* in_sizes, int n_in,
                              void* d_out, int out_size, void* d_ws, size_t ws_size,
                              hipStream_t stream) {
    const float* x      = (const float*)d_in[0];
    const float* W_in   = (const float*)d_in[1];
    const float* b_in   = (const float*)d_in[2];
    const float* conv_w = (const float*)d_in[3];
    const float* nbias  = (const float*)d_in[4];
    const float* W_out  = (const float*)d_in[5];
    const float* b_out  = (const float*)d_in[6];
    const int*   steps  = (const int*)d_in[7];
    float* out = (float*)d_out;
    float* surface = (float*)d_ws;   // 1024*1024 f32 = 4 MB scratch

    in_gemm<<<dim3(16, 16), 256, 0, stream>>>(x, W_in, b_in, surface);
    cube_evolve<<<1024, dim3(16, 32), 0, stream>>>(surface, conv_w, nbias,
                                                   W_out, b_out, steps, out);
}

// Round 10
// 1865.870 us; speedup vs baseline: 1.3399x; 1.3399x over previous
//
#include <hip/hip_runtime.h>

#define CUBE 32

__device__ __forceinline__ float sgpr_f(float v) {
    int i = __builtin_amdgcn_readfirstlane(__float_as_int(v));
    return __int_as_float(i);
}

// ---------------- Kernel A: surface = x @ W_in^T + b_in ----------------
__global__ __launch_bounds__(256) void in_gemm(
    const float* __restrict__ x,
    const float* __restrict__ W_in,
    const float* __restrict__ b_in,
    float* __restrict__ surface)
{
    __shared__ __align__(16) float As[16][68];
    __shared__ __align__(16) float Bs[16][68];
    const int t  = threadIdx.x;
    const int tx = t & 15, ty = t >> 4;
    const int bn = blockIdx.x * 64;
    const int bb = blockIdx.y * 64;

    float acc[4][4];
#pragma unroll
    for (int i = 0; i < 4; ++i)
#pragma unroll
        for (int j = 0; j < 4; ++j) acc[i][j] = 0.0f;

    for (int k0 = 0; k0 < 784; k0 += 16) {
        const int e  = t * 4;
        const int r  = e >> 4;
        const int kk = e & 15;
        float4 av = *(const float4*)&x[(size_t)(bb + r) * 784 + k0 + kk];
        float4 bv = *(const float4*)&W_in[(size_t)(bn + r) * 784 + k0 + kk];
        As[kk + 0][r] = av.x; As[kk + 1][r] = av.y; As[kk + 2][r] = av.z; As[kk + 3][r] = av.w;
        Bs[kk + 0][r] = bv.x; Bs[kk + 1][r] = bv.y; Bs[kk + 2][r] = bv.z; Bs[kk + 3][r] = bv.w;
        __syncthreads();
#pragma unroll
        for (int kki = 0; kki < 16; ++kki) {
            float4 a = *(const float4*)&As[kki][ty * 4];
            float4 b = *(const float4*)&Bs[kki][tx * 4];
            float aa[4] = {a.x, a.y, a.z, a.w};
            float bbv[4] = {b.x, b.y, b.z, b.w};
#pragma unroll
            for (int i = 0; i < 4; ++i)
#pragma unroll
                for (int j = 0; j < 4; ++j)
                    acc[i][j] = fmaf(aa[i], bbv[j], acc[i][j]);
        }
        __syncthreads();
    }
#pragma unroll
    for (int i = 0; i < 4; ++i) {
        const int row = bb + ty * 4 + i;
#pragma unroll
        for (int j = 0; j < 4; ++j) {
            const int col = bn + tx * 4 + j;
            surface[(size_t)row * 1024 + col] = acc[i][j] + b_in[col];
        }
    }
}

// ---------------- Kernel B: cube evolution + output GEMM -----------------
// 1024 threads (32×32), 1 voxel/thread, f32 state in LDS S[32][34][34]
// (y,x halo'd, borders stay 0). r7's verified numerics, two scheduling fixes:
//  * 16 waves/block = 4 waves/SIMD (r7 had 2): real stall fraction was ~60%
//    (VALUBusy derived counter is ~2x inflated on gfx950 — gfx94x formula
//    assumes 4-cyc wave64 issue, CDNA4 SIMD-32 issues in 2).
//  * software pipeline: phase p prefetch-reads plane p+1's 9-value window
//    (plane p+1 is not written until phase p+2 -> race-free at <=1 phase
//    barrier skew) and loads nb one phase ahead. b32 reads here are 2
//    lanes/bank = conflict-free.

#define REP32(M) M(0)M(1)M(2)M(3)M(4)M(5)M(6)M(7)M(8)M(9)M(10)M(11)M(12)M(13)M(14)M(15)M(16)M(17)M(18)M(19)M(20)M(21)M(22)M(23)M(24)M(25)M(26)M(27)M(28)M(29)M(30)M(31)

#define LOADW(R, pp)                                                           \
    R##0 = S[pp][ty+0][tx+0]; R##1 = S[pp][ty+0][tx+1]; R##2 = S[pp][ty+0][tx+2]; \
    R##3 = S[pp][ty+1][tx+0]; R##4 = S[pp][ty+1][tx+1]; R##5 = S[pp][ty+1][tx+2]; \
    R##6 = S[pp][ty+2][tx+0]; R##7 = S[pp][ty+2][tx+1]; R##8 = S[pp][ty+2][tx+2];

#define FMA_N(a, R)                                                            \
    a = fmaf(cw0, R##0, a); a = fmaf(cw1, R##1, a); a = fmaf(cw2, R##2, a);    \
    a = fmaf(cw3, R##3, a); a = fmaf(cw4, R##4, a); a = fmaf(cw5, R##5, a);    \
    a = fmaf(cw6, R##6, a); a = fmaf(cw7, R##7, a); a = fmaf(cw8, R##8, a);
#define FMA_C(a, R)                                                            \
    a = fmaf(cw9,  R##0, a); a = fmaf(cw10, R##1, a); a = fmaf(cw11, R##2, a); \
    a = fmaf(cw12, R##3, a); a = fmaf(cw13, R##4, a); a = fmaf(cw14, R##5, a); \
    a = fmaf(cw15, R##6, a); a = fmaf(cw16, R##7, a); a = fmaf(cw17, R##8, a);
#define FMA_P(a, R)                                                            \
    a = fmaf(cw18, R##0, a); a = fmaf(cw19, R##1, a); a = fmaf(cw20, R##2, a); \
    a = fmaf(cw21, R##3, a); a = fmaf(cw22, R##4, a); a = fmaf(cw23, R##5, a); \
    a = fmaf(cw24, R##6, a); a = fmaf(cw25, R##7, a); a = fmaf(cw26, R##8, a);

// Phase p: consume CUR (plane p window, prefetched in phase p-1); prefetch
// NXT <- plane p+1; finalize output q = p-1 (tanh + blend, in-place write).
#define PLANE(p, q, CUR, NXT, aN, aC, aP) {                                    \
    __syncthreads();                                                           \
    nb_##p = nbp[(p) * 1024];                                                  \
    if ((p) < 31) { LOADW(NXT, (p)+1) }                                        \
    if ((p) < 31) { FMA_N(aN, CUR) }                                           \
    FMA_C(aC, CUR)                                                             \
    if ((p) >= 1) {                                                            \
        FMA_P(aP, CUR)                                                         \
        const float pre = aP + nb_##q + (((q) == 0) ? surf : 0.0f);            \
        const float tE  = __builtin_amdgcn_exp2f(pre * 2.8853900817779268f);   \
        const float h   = 1.0f - 2.0f * __builtin_amdgcn_rcpf(tE + 1.0f);      \
        S[q][ty + 1][tx + 1] = 0.5f * (cc + h);                                \
        aP = 0.0f;                                                             \
    }                                                                          \
    cc = CUR##4;                                                               \
}

__global__ __launch_bounds__(1024) void cube_evolve(
    const float* __restrict__ surface,   // [1024][1024]
    const float* __restrict__ conv_w,    // [27]  (kd,ky,kx)
    const float* __restrict__ nbias,     // [32768] (d,y,x)
    const float* __restrict__ W_out,     // [10][32768]
    const float* __restrict__ b_out,     // [10]
    const int*   __restrict__ steps_p,   // [1]
    float* __restrict__ out)             // [1024][10]
{
    __shared__ float S[32][34][34];      // 147,968 B; halo rows/cols stay 0
    __shared__ float red[10][16];

    const int b   = blockIdx.x;
    const int tx  = threadIdx.x;         // x: 0..31
    const int ty  = threadIdx.y;         // y: 0..31
    const int tid = ty * 32 + tx;
    const int steps = steps_p[0];

    // zero state + halos
    for (int i = tid; i < 32 * 34 * 34; i += 1024) ((float*)S)[i] = 0.0f;

    // conv weights -> uniform scalars (SGPRs)
    const float cw0  = sgpr_f(conv_w[0]),  cw1  = sgpr_f(conv_w[1]),  cw2  = sgpr_f(conv_w[2]);
    const float cw3  = sgpr_f(conv_w[3]),  cw4  = sgpr_f(conv_w[4]),  cw5  = sgpr_f(conv_w[5]);
    const float cw6  = sgpr_f(conv_w[6]),  cw7  = sgpr_f(conv_w[7]),  cw8  = sgpr_f(conv_w[8]);
    const float cw9  = sgpr_f(conv_w[9]),  cw10 = sgpr_f(conv_w[10]), cw11 = sgpr_f(conv_w[11]);
    const float cw12 = sgpr_f(conv_w[12]), cw13 = sgpr_f(conv_w[13]), cw14 = sgpr_f(conv_w[14]);
    const float cw15 = sgpr_f(conv_w[15]), cw16 = sgpr_f(conv_w[16]), cw17 = sgpr_f(conv_w[17]);
    const float cw18 = sgpr_f(conv_w[18]), cw19 = sgpr_f(conv_w[19]), cw20 = sgpr_f(conv_w[20]);
    const float cw21 = sgpr_f(conv_w[21]), cw22 = sgpr_f(conv_w[22]), cw23 = sgpr_f(conv_w[23]);
    const float cw24 = sgpr_f(conv_w[24]), cw25 = sgpr_f(conv_w[25]), cw26 = sgpr_f(conv_w[26]);

    const float* nbp = nbias + tid;
    const float  surf = surface[(size_t)b * 1024 + tid];

    float w0, w1, w2, w3, w4, w5, w6, w7, w8;   // window: even planes
    float v0, v1, v2, v3, v4, v5, v6, v7, v8;   // window: odd planes

    __syncthreads();
    LOADW(w, 0)                                  // prologue prefetch (zeros)

    for (int st = 0; st < steps; ++st) {
#define DECL_NB(d) float nb_##d;
        REP32(DECL_NB)
#undef DECL_NB
        float a0 = 0.f, a1 = 0.f, a2 = 0.f;
        float cc = 0.f;
        // aN = a[(p+1)%3], aC = a[p%3], aP = a[(p+2)%3]; CUR/NXT by parity
        PLANE( 0,  0, w, v, a1, a0, a2)
        PLANE( 1,  0, v, w, a2, a1, a0)
        PLANE( 2,  1, w, v, a0, a2, a1)
        PLANE( 3,  2, v, w, a1, a0, a2)
        PLANE( 4,  3, w, v, a2, a1, a0)
        PLANE( 5,  4, v, w, a0, a2, a1)
        PLANE( 6,  5, w, v, a1, a0, a2)
        PLANE( 7,  6, v, w, a2, a1, a0)
        PLANE( 8,  7, w, v, a0, a2, a1)
        PLANE( 9,  8, v, w, a1, a0, a2)
        PLANE(10,  9, w, v, a2, a1, a0)
        PLANE(11, 10, v, w, a0, a2, a1)
        PLANE(12, 11, w, v, a1, a0, a2)
        PLANE(13, 12, v, w, a2, a1, a0)
        PLANE(14, 13, w, v, a0, a2, a1)
        PLANE(15, 14, v, w, a1, a0, a2)
        PLANE(16, 15, w, v, a2, a1, a0)
        PLANE(17, 16, v, w, a0, a2, a1)
        PLANE(18, 17, w, v, a1, a0, a2)
        PLANE(19, 18, v, w, a2, a1, a0)
        PLANE(20, 19, w, v, a0, a2, a1)
        PLANE(21, 20, v, w, a1, a0, a2)
        PLANE(22, 21, w, v, a2, a1, a0)
        PLANE(23, 22, v, w, a0, a2, a1)
        PLANE(24, 23, w, v, a1, a0, a2)
        PLANE(25, 24, v, w, a2, a1, a0)
        PLANE(26, 25, w, v, a0, a2, a1)
        PLANE(27, 26, v, w, a1, a0, a2)
        PLANE(28, 27, w, v, a2, a1, a0)
        PLANE(29, 28, v, w, a0, a2, a1)
        PLANE(30, 29, w, v, a1, a0, a2)
        PLANE(31, 30, v, w, a2, a1, a0)
        { // finalize output plane 31: kd=0 from plane 30 (aN=a1) + kd=1 from
          // plane 31 (aC=a1); cc = plane 31 center (v4, captured in PLANE 31)
            const float pre = a1 + nb_31;
            const float tE  = __builtin_amdgcn_exp2f(pre * 2.8853900817779268f);
            const float h   = 1.0f - 2.0f * __builtin_amdgcn_rcpf(tE + 1.0f);
            __syncthreads();   // all phase-31 work done before overwrite
            S[31][ty + 1][tx + 1] = 0.5f * (cc + h);
            LOADW(w, 0)        // prefetch plane 0 (new value) for next step
        }
    }
    __syncthreads();   // state complete & visible

    // ---- fused output GEMM: out[b][o] = sum_flat s * W_out[o][flat] + b_out[o]
    float p0 = 0.f, p1 = 0.f, p2 = 0.f, p3 = 0.f, p4 = 0.f;
    float p5 = 0.f, p6 = 0.f, p7 = 0.f, p8 = 0.f, p9 = 0.f;
    const int base = tid * 4;
#pragma unroll
    for (int j = 0; j < 8; ++j) {
        const int idx = base + j * 4096;
        const int d   = idx >> 10;
        const int rem = idx & 1023;
        const int yy  = rem >> 5;
        const int xx  = rem & 31;
        const float s0v = S[d][yy + 1][xx + 1];
        const float s1v = S[d][yy + 1][xx + 2];
        const float s2v = S[d][yy + 1][xx + 3];
        const float s3v = S[d][yy + 1][xx + 4];
#define OACC(o) { const float4 wv = *(const float4*)&W_out[(size_t)(o) * 32768 + idx]; \
        p##o = fmaf(s0v, wv.x, p##o); p##o = fmaf(s1v, wv.y, p##o);            \
        p##o = fmaf(s2v, wv.z, p##o); p##o = fmaf(s3v, wv.w, p##o); }
        OACC(0) OACC(1) OACC(2) OACC(3) OACC(4)
        OACC(5) OACC(6) OACC(7) OACC(8) OACC(9)
#undef OACC
    }

    const int lane = tid & 63, wvi = tid >> 6;
#define RED(o) { float t = p##o;                                               \
    t += __shfl_down(t, 32, 64); t += __shfl_down(t, 16, 64);                  \
    t += __shfl_down(t, 8, 64);  t += __shfl_down(t, 4, 64);                   \
    t += __shfl_down(t, 2, 64);  t += __shfl_down(t, 1, 64);                   \
    if (lane == 0) red[o][wvi] = t; }
    RED(0) RED(1) RED(2) RED(3) RED(4) RED(5) RED(6) RED(7) RED(8) RED(9)
#undef RED
    __syncthreads();
    if (tid < 10) {
        float sum = b_out[tid];
#pragma unroll
        for (int w16 = 0; w16 < 16; ++w16) sum += red[tid][w16];
        out[(size_t)b * 10 + tid] = sum;
    }
}

// ---------------- launcher ----------------
extern "C" void kernel_launch(void* const* d_in, const int* in_sizes, int n_in,
                              void* d_out, int out_size, void* d_ws, size_t ws_size,
                              hipStream_t stream) {
    const float* x      = (const float*)d_in[0];
    const float* W_in   = (const float*)d_in[1];
    const float* b_in   = (const float*)d_in[2];
    const float* conv_w = (const float*)d_in[3];
    const float* nbias  = (const float*)d_in[4];
    const float* W_out  = (const float*)d_in[5];
    const float* b_out  = (const float*)d_in[6];
    const int*   steps  = (const int*)d_in[7];
    float* out = (float*)d_out;
    float* surface = (float*)d_ws;   // 1024*1024 f32 = 4 MB scratch

    in_gemm<<<dim3(16, 16), 256, 0, stream>>>(x, W_in, b_in, surface);
    cube_evolve<<<1024, dim3(32, 32), 0, stream>>>(surface, conv_w, nbias,
                                                   W_out, b_out, steps, out);
}

// Round 11
// 1196.815 us; speedup vs baseline: 2.0889x; 1.5590x over previous
//
#include <hip/hip_runtime.h>

#define CUBE 32

__device__ __forceinline__ float sgpr_f(float v) {
    int i = __builtin_amdgcn_readfirstlane(__float_as_int(v));
    return __int_as_float(i);
}

// ---------------- Kernel A: surface = x @ W_in^T + b_in ----------------
__global__ __launch_bounds__(256) void in_gemm(
    const float* __restrict__ x,
    const float* __restrict__ W_in,
    const float* __restrict__ b_in,
    float* __restrict__ surface)
{
    __shared__ __align__(16) float As[16][68];
    __shared__ __align__(16) float Bs[16][68];
    const int t  = threadIdx.x;
    const int tx = t & 15, ty = t >> 4;
    const int bn = blockIdx.x * 64;
    const int bb = blockIdx.y * 64;

    float acc[4][4];
#pragma unroll
    for (int i = 0; i < 4; ++i)
#pragma unroll
        for (int j = 0; j < 4; ++j) acc[i][j] = 0.0f;

    for (int k0 = 0; k0 < 784; k0 += 16) {
        const int e  = t * 4;
        const int r  = e >> 4;
        const int kk = e & 15;
        float4 av = *(const float4*)&x[(size_t)(bb + r) * 784 + k0 + kk];
        float4 bv = *(const float4*)&W_in[(size_t)(bn + r) * 784 + k0 + kk];
        As[kk + 0][r] = av.x; As[kk + 1][r] = av.y; As[kk + 2][r] = av.z; As[kk + 3][r] = av.w;
        Bs[kk + 0][r] = bv.x; Bs[kk + 1][r] = bv.y; Bs[kk + 2][r] = bv.z; Bs[kk + 3][r] = bv.w;
        __syncthreads();
#pragma unroll
        for (int kki = 0; kki < 16; ++kki) {
            float4 a = *(const float4*)&As[kki][ty * 4];
            float4 b = *(const float4*)&Bs[kki][tx * 4];
            float aa[4] = {a.x, a.y, a.z, a.w};
            float bbv[4] = {b.x, b.y, b.z, b.w};
#pragma unroll
            for (int i = 0; i < 4; ++i)
#pragma unroll
                for (int j = 0; j < 4; ++j)
                    acc[i][j] = fmaf(aa[i], bbv[j], acc[i][j]);
        }
        __syncthreads();
    }
#pragma unroll
    for (int i = 0; i < 4; ++i) {
        const int row = bb + ty * 4 + i;
#pragma unroll
        for (int j = 0; j < 4; ++j) {
            const int col = bn + tx * 4 + j;
            surface[(size_t)row * 1024 + col] = acc[i][j] + b_in[col];
        }
    }
}

// ---------------- Kernel B: cube evolution + output GEMM -----------------
// r7 structure verbatim (512 thr = 16xg × 32y, 2 voxels/thread, f32 state in
// LDS S[32][34][34], halo'd, in-place plane update) with ONE change:
// 4-deep write pipeline. Phase p finalizes output p-1 into a rotating pend
// register slot (pd[(p+2)%3], 3 slots/voxel) and defers the LDS write of
// plane p-4 to phase p. Write-delay(4) >= barrier-interval(4) => writes of
// planes [4k-4,4k) and reads of planes [4k,4k+4) are separated by the
// barrier at phase 4k. Barriers/step: 32 -> 9 (r7's ~600cy/phase stall was
// barrier drain at 2 waves/SIMD).

#define REP32(M) M(0)M(1)M(2)M(3)M(4)M(5)M(6)M(7)M(8)M(9)M(10)M(11)M(12)M(13)M(14)M(15)M(16)M(17)M(18)M(19)M(20)M(21)M(22)M(23)M(24)M(25)M(26)M(27)M(28)M(29)M(30)M(31)

// out0 (x=2tx): l,c,r = A.x,A.y,B.x ; out1 (x=2tx+1): A.y,B.x,B.y
#define ROW3(v0a, v1a, wl, wc, wr, A, B)                                       \
    v0a = fmaf(wl, A.x, v0a); v0a = fmaf(wc, A.y, v0a); v0a = fmaf(wr, B.x, v0a); \
    v1a = fmaf(wl, A.y, v1a); v1a = fmaf(wc, B.x, v1a); v1a = fmaf(wr, B.y, v1a);

// Phase p: barrier every 4 phases; read plane-p window; write plane p-4 from
// pend; accumulate aN(out p+1)/aC(out p)/aP(out p-1); finalize out p-1 into
// the SAME pend slot just written (slot (p+2)%3).
#define PLANE(p, q, w4, aN0, aN1, aC0, aC1, aP0, aP1, PD0, PD1) {              \
    if ((p) % 4 == 0) __syncthreads();                                         \
    nb_##p = *(const float2*)&nbias[(p) * 1024 + nboff];                       \
    const float2 A0 = *(const float2*)&S[p][ty + 0][tx2];                      \
    const float2 B0 = *(const float2*)&S[p][ty + 0][tx2 + 2];                  \
    const float2 A1 = *(const float2*)&S[p][ty + 1][tx2];                      \
    const float2 B1 = *(const float2*)&S[p][ty + 1][tx2 + 2];                  \
    const float2 A2 = *(const float2*)&S[p][ty + 2][tx2];                      \
    const float2 B2 = *(const float2*)&S[p][ty + 2][tx2 + 2];                  \
    if ((p) >= 4) {                                                            \
        S[w4][ty + 1][tx2 + 1] = PD0;                                          \
        S[w4][ty + 1][tx2 + 2] = PD1;                                          \
    }                                                                          \
    if ((p) < 31) {                                                            \
        ROW3(aN0, aN1, cw0, cw1, cw2, A0, B0)                                  \
        ROW3(aN0, aN1, cw3, cw4, cw5, A1, B1)                                  \
        ROW3(aN0, aN1, cw6, cw7, cw8, A2, B2)                                  \
    }                                                                          \
    ROW3(aC0, aC1, cw9,  cw10, cw11, A0, B0)                                   \
    ROW3(aC0, aC1, cw12, cw13, cw14, A1, B1)                                   \
    ROW3(aC0, aC1, cw15, cw16, cw17, A2, B2)                                   \
    if ((p) >= 1) {                                                            \
        ROW3(aP0, aP1, cw18, cw19, cw20, A0, B0)                               \
        ROW3(aP0, aP1, cw21, cw22, cw23, A1, B1)                               \
        ROW3(aP0, aP1, cw24, cw25, cw26, A2, B2)                               \
        const float pre0 = aP0 + nb_##q.x + (((q) == 0) ? sf0 : 0.0f);         \
        const float pre1 = aP1 + nb_##q.y + (((q) == 0) ? sf1 : 0.0f);         \
        const float h0 = 1.0f - 2.0f * __builtin_amdgcn_rcpf(                  \
            __builtin_amdgcn_exp2f(pre0 * 2.8853900817779268f) + 1.0f);        \
        const float h1 = 1.0f - 2.0f * __builtin_amdgcn_rcpf(                  \
            __builtin_amdgcn_exp2f(pre1 * 2.8853900817779268f) + 1.0f);        \
        PD0 = 0.5f * (cc0 + h0);                                               \
        PD1 = 0.5f * (cc1 + h1);                                               \
        aP0 = 0.0f; aP1 = 0.0f;                                                \
    }                                                                          \
    cc0 = A1.y; cc1 = B1.x;                                                    \
}

__global__ __launch_bounds__(512) void cube_evolve(
    const float* __restrict__ surface,   // [1024][1024]
    const float* __restrict__ conv_w,    // [27]  (kd,ky,kx)
    const float* __restrict__ nbias,     // [32768] (d,y,x)
    const float* __restrict__ W_out,     // [10][32768]
    const float* __restrict__ b_out,     // [10]
    const int*   __restrict__ steps_p,   // [1]
    float* __restrict__ out)             // [1024][10]
{
    __shared__ float S[32][34][34];      // 147,968 B; halo rows/cols stay 0
    __shared__ float red[10][8];

    const int b   = blockIdx.x;
    const int tx  = threadIdx.x;         // 0..15, owns x = 2tx, 2tx+1
    const int ty  = threadIdx.y;         // 0..31
    const int tid = ty * 16 + tx;
    const int tx2 = tx * 2;              // halo-coord base of the 4-wide window
    const int nboff = ty * 32 + tx2;
    const int steps = steps_p[0];

    // zero state + halos
    for (int i = tid; i < 32 * 34 * 34; i += 512) ((float*)S)[i] = 0.0f;

    // conv weights -> uniform scalars (SGPRs)
    const float cw0  = sgpr_f(conv_w[0]),  cw1  = sgpr_f(conv_w[1]),  cw2  = sgpr_f(conv_w[2]);
    const float cw3  = sgpr_f(conv_w[3]),  cw4  = sgpr_f(conv_w[4]),  cw5  = sgpr_f(conv_w[5]);
    const float cw6  = sgpr_f(conv_w[6]),  cw7  = sgpr_f(conv_w[7]),  cw8  = sgpr_f(conv_w[8]);
    const float cw9  = sgpr_f(conv_w[9]),  cw10 = sgpr_f(conv_w[10]), cw11 = sgpr_f(conv_w[11]);
    const float cw12 = sgpr_f(conv_w[12]), cw13 = sgpr_f(conv_w[13]), cw14 = sgpr_f(conv_w[14]);
    const float cw15 = sgpr_f(conv_w[15]), cw16 = sgpr_f(conv_w[16]), cw17 = sgpr_f(conv_w[17]);
    const float cw18 = sgpr_f(conv_w[18]), cw19 = sgpr_f(conv_w[19]), cw20 = sgpr_f(conv_w[20]);
    const float cw21 = sgpr_f(conv_w[21]), cw22 = sgpr_f(conv_w[22]), cw23 = sgpr_f(conv_w[23]);
    const float cw24 = sgpr_f(conv_w[24]), cw25 = sgpr_f(conv_w[25]), cw26 = sgpr_f(conv_w[26]);

    const float2 sfv = *(const float2*)&surface[(size_t)b * 1024 + nboff];
    const float sf0 = sfv.x, sf1 = sfv.y;

    for (int st = 0; st < steps; ++st) {
#define DECL_NB(d) float2 nb_##d;
        REP32(DECL_NB)
#undef DECL_NB
        float a00 = 0.f, a01 = 0.f, a10 = 0.f, a11 = 0.f, a20 = 0.f, a21 = 0.f;
        float pd00, pd01, pd10, pd11, pd20, pd21;   // pend slots 0,1,2 × 2 vox
        float cc0 = 0.f, cc1 = 0.f;
        // (aN, aC, aP) = slots ((p+1)%3, p%3, (p+2)%3); PD = slot (p+2)%3
        PLANE( 0,  0,  0, a10,a11, a00,a01, a20,a21, pd20,pd21)
        PLANE( 1,  0,  0, a20,a21, a10,a11, a00,a01, pd00,pd01)
        PLANE( 2,  1,  0, a00,a01, a20,a21, a10,a11, pd10,pd11)
        PLANE( 3,  2,  0, a10,a11, a00,a01, a20,a21, pd20,pd21)
        PLANE( 4,  3,  0, a20,a21, a10,a11, a00,a01, pd00,pd01)
        PLANE( 5,  4,  1, a00,a01, a20,a21, a10,a11, pd10,pd11)
        PLANE( 6,  5,  2, a10,a11, a00,a01, a20,a21, pd20,pd21)
        PLANE( 7,  6,  3, a20,a21, a10,a11, a00,a01, pd00,pd01)
        PLANE( 8,  7,  4, a00,a01, a20,a21, a10,a11, pd10,pd11)
        PLANE( 9,  8,  5, a10,a11, a00,a01, a20,a21, pd20,pd21)
        PLANE(10,  9,  6, a20,a21, a10,a11, a00,a01, pd00,pd01)
        PLANE(11, 10,  7, a00,a01, a20,a21, a10,a11, pd10,pd11)
        PLANE(12, 11,  8, a10,a11, a00,a01, a20,a21, pd20,pd21)
        PLANE(13, 12,  9, a20,a21, a10,a11, a00,a01, pd00,pd01)
        PLANE(14, 13, 10, a00,a01, a20,a21, a10,a11, pd10,pd11)
        PLANE(15, 14, 11, a10,a11, a00,a01, a20,a21, pd20,pd21)
        PLANE(16, 15, 12, a20,a21, a10,a11, a00,a01, pd00,pd01)
        PLANE(17, 16, 13, a00,a01, a20,a21, a10,a11, pd10,pd11)
        PLANE(18, 17, 14, a10,a11, a00,a01, a20,a21, pd20,pd21)
        PLANE(19, 18, 15, a20,a21, a10,a11, a00,a01, pd00,pd01)
        PLANE(20, 19, 16, a00,a01, a20,a21, a10,a11, pd10,pd11)
        PLANE(21, 20, 17, a10,a11, a00,a01, a20,a21, pd20,pd21)
        PLANE(22, 21, 18, a20,a21, a10,a11, a00,a01, pd00,pd01)
        PLANE(23, 22, 19, a00,a01, a20,a21, a10,a11, pd10,pd11)
        PLANE(24, 23, 20, a10,a11, a00,a01, a20,a21, pd20,pd21)
        PLANE(25, 24, 21, a20,a21, a10,a11, a00,a01, pd00,pd01)
        PLANE(26, 25, 22, a00,a01, a20,a21, a10,a11, pd10,pd11)
        PLANE(27, 26, 23, a10,a11, a00,a01, a20,a21, pd20,pd21)
        PLANE(28, 27, 24, a20,a21, a10,a11, a00,a01, pd00,pd01)
        PLANE(29, 28, 25, a00,a01, a20,a21, a10,a11, pd10,pd11)
        PLANE(30, 29, 26, a10,a11, a00,a01, a20,a21, pd20,pd21)
        PLANE(31, 30, 27, a20,a21, a10,a11, a00,a01, pd00,pd01)
        { // tail: finalize output 31 (aC of phase 31 = slot1) and flush
          // pending planes 28(pd1), 29(pd2), 30(pd0), 31.
            const float pre0 = a10 + nb_31.x;
            const float pre1 = a11 + nb_31.y;
            const float h0 = 1.0f - 2.0f * __builtin_amdgcn_rcpf(
                __builtin_amdgcn_exp2f(pre0 * 2.8853900817779268f) + 1.0f);
            const float h1 = 1.0f - 2.0f * __builtin_amdgcn_rcpf(
                __builtin_amdgcn_exp2f(pre1 * 2.8853900817779268f) + 1.0f);
            const float v310 = 0.5f * (cc0 + h0);
            const float v311 = 0.5f * (cc1 + h1);
            __syncthreads();   // waves may still be reading planes 28..31
            S[28][ty + 1][tx2 + 1] = pd10; S[28][ty + 1][tx2 + 2] = pd11;
            S[29][ty + 1][tx2 + 1] = pd20; S[29][ty + 1][tx2 + 2] = pd21;
            S[30][ty + 1][tx2 + 1] = pd00; S[30][ty + 1][tx2 + 2] = pd01;
            S[31][ty + 1][tx2 + 1] = v310; S[31][ty + 1][tx2 + 2] = v311;
        }
    }
    __syncthreads();   // state complete & visible

    // ---- fused output GEMM: out[b][o] = sum_flat s * W_out[o][flat] + b_out[o]
    float p0 = 0.f, p1 = 0.f, p2 = 0.f, p3 = 0.f, p4 = 0.f;
    float p5 = 0.f, p6 = 0.f, p7 = 0.f, p8 = 0.f, p9 = 0.f;
    const int base = tid * 4;
#pragma unroll 4
    for (int j = 0; j < 16; ++j) {
        const int idx = base + j * 2048;
        const int d   = idx >> 10;
        const int rem = idx & 1023;
        const int yy  = rem >> 5;
        const int xx  = rem & 31;
        const float s0v = S[d][yy + 1][xx + 1];
        const float s1v = S[d][yy + 1][xx + 2];
        const float s2v = S[d][yy + 1][xx + 3];
        const float s3v = S[d][yy + 1][xx + 4];
#define OACC(o) { const float4 wv = *(const float4*)&W_out[(size_t)(o) * 32768 + idx]; \
        p##o = fmaf(s0v, wv.x, p##o); p##o = fmaf(s1v, wv.y, p##o);            \
        p##o = fmaf(s2v, wv.z, p##o); p##o = fmaf(s3v, wv.w, p##o); }
        OACC(0) OACC(1) OACC(2) OACC(3) OACC(4)
        OACC(5) OACC(6) OACC(7) OACC(8) OACC(9)
#undef OACC
    }

    const int lane = tid & 63, wvi = tid >> 6;
#define RED(o) { float t = p##o;                                               \
    t += __shfl_down(t, 32, 64); t += __shfl_down(t, 16, 64);                  \
    t += __shfl_down(t, 8, 64);  t += __shfl_down(t, 4, 64);                   \
    t += __shfl_down(t, 2, 64);  t += __shfl_down(t, 1, 64);                   \
    if (lane == 0) red[o][wvi] = t; }
    RED(0) RED(1) RED(2) RED(3) RED(4) RED(5) RED(6) RED(7) RED(8) RED(9)
#undef RED
    __syncthreads();
    if (tid < 10) {
        float sum = b_out[tid];
#pragma unroll
        for (int w8 = 0; w8 < 8; ++w8) sum += red[tid][w8];
        out[(size_t)b * 10 + tid] = sum;
    }
}

// ---------------- launcher ----------------
extern "C" void kernel_launch(void* const* d_in, const int* in_sizes, int n_in,
                              void* d_out, int out_size, void* d_ws, size_t ws_size,
                              hipStream_t stream) {
    const float* x      = (const float*)d_in[0];
    const float* W_in   = (const float*)d_in[1];
    const float* b_in   = (const float*)d_in[2];
    const float* conv_w = (const float*)d_in[3];
    const float* nbias  = (const float*)d_in[4];
    const float* W_out  = (const float*)d_in[5];
    const float* b_out  = (const float*)d_in[6];
    const int*   steps  = (const int*)d_in[7];
    float* out = (float*)d_out;
    float* surface = (float*)d_ws;   // 1024*1024 f32 = 4 MB scratch

    in_gemm<<<dim3(16, 16), 256, 0, stream>>>(x, W_in, b_in, surface);
    cube_evolve<<<1024, dim3(16, 32), 0, stream>>>(surface, conv_w, nbias,
                                                   W_out, b_out, steps, out);
}